// Round 13
// baseline (410.814 us; speedup 1.0000x reference)
//
#include <hip/hip_runtime.h>
#include <math.h>

#define BB 1024
#define LL 40
#define RR 1024

using short8 = __attribute__((ext_vector_type(8))) short;
using us8    = __attribute__((ext_vector_type(8))) unsigned short;
using f32x4  = __attribute__((ext_vector_type(4))) float;

__device__ __forceinline__ ushort f2bf(float f) {
    union { float f; unsigned u; } a; a.f = f;
    unsigned r = a.u + 0x7fffu + ((a.u >> 16) & 1u);  // RNE
    return (ushort)(r >> 16);
}
__device__ __forceinline__ float bf2f(ushort u) {
    union { unsigned u; float f; } a; a.u = ((unsigned)u) << 16;
    return a.f;
}
__device__ __forceinline__ float ftanh(float x) {
    float cx = fminf(fmaxf(x, -15.f), 15.f);
    float e = __expf(2.f * cx);
    return (e - 1.f) / (e + 1.f);
}
__device__ __forceinline__ float fsigmoid(float x) {
    float cx = fminf(fmaxf(x, -30.f), 30.f);
    return 1.f / (1.f + __expf(-cx));
}

__device__ __forceinline__ void gll16(const ushort* g, ushort* l) {
    __builtin_amdgcn_global_load_lds(
        (const __attribute__((address_space(1))) void*)g,
        (__attribute__((address_space(3))) void*)l,
        16, 0, 0);
}

// ---------------------------------------------------------------------------
__global__ __launch_bounds__(256) void conv_bf16_kernel(
    const float* __restrict__ src, ushort* __restrict__ dst, int n8)
{
    const int i = blockIdx.x * 256 + threadIdx.x;
    if (i >= n8) return;
    const float4* s4 = (const float4*)(src + (size_t)i * 8);
    float4 x = s4[0], y = s4[1];
    us8 v;
    v[0] = f2bf(x.x); v[1] = f2bf(x.y); v[2] = f2bf(x.z); v[3] = f2bf(x.w);
    v[4] = f2bf(y.x); v[5] = f2bf(y.y); v[6] = f2bf(y.z); v[7] = f2bf(y.w);
    ((us8*)dst)[i] = v;
}

struct CP3 { const float* in[3]; ushort* out[3]; };
__global__ __launch_bounds__(256) void conv_bf16_batch3_kernel(CP3 p, int n8)
{
    const int z = blockIdx.y;
    const int i = blockIdx.x * 256 + threadIdx.x;
    if (i >= n8) return;
    const float4* s4 = (const float4*)(p.in[z] + (size_t)i * 8);
    float4 x = s4[0], y = s4[1];
    us8 v;
    v[0] = f2bf(x.x); v[1] = f2bf(x.y); v[2] = f2bf(x.z); v[3] = f2bf(x.w);
    v[4] = f2bf(y.x); v[5] = f2bf(y.y); v[6] = f2bf(y.z); v[7] = f2bf(y.w);
    ((us8*)p.out[z])[i] = v;
}

struct TP6 { const float* in[6]; ushort* out[6]; int N[6]; };
__global__ __launch_bounds__(256) void transpose_conv_kernel(TP6 p)
{
    const int z = blockIdx.z;
    const int Nn = p.N[z];
    const int n0 = blockIdx.x * 64;
    if (n0 >= Nn) return;
    const int k0 = blockIdx.y * 64;
    const float* in = p.in[z];
    ushort* out = p.out[z];

    __shared__ float tile[64][65];
    const int t = threadIdx.x;
    const int tx = t & 63, ty = t >> 6;
#pragma unroll
    for (int r = 0; r < 16; ++r) {
        const int row = ty * 16 + r;
        tile[row][tx] = in[(size_t)(k0 + row) * Nn + n0 + tx];
    }
    __syncthreads();
    const int n = t >> 2, kq = t & 3;
    us8 v0, v1;
#pragma unroll
    for (int j = 0; j < 8; ++j) v0[j] = f2bf(tile[kq * 16 + j][n]);
#pragma unroll
    for (int j = 0; j < 8; ++j) v1[j] = f2bf(tile[kq * 16 + 8 + j][n]);
    ushort* op = out + (size_t)(n0 + n) * 1024 + k0 + kq * 16;
    *(us8*)op = v0;
    *((us8*)op + 1) = v1;
}

// ---------------------------------------------------------------------------
// R8-proven 128x128 BK=64 4-wave GEMM (single-buffer, XOR swizzle).
// For the small hq/gate GEMMs. bf16 split-K partial store.
// ---------------------------------------------------------------------------
template <int NP, int SK>
__global__ __launch_bounds__(256) void gemm_gl(
    const ushort* __restrict__ A0, const ushort* __restrict__ A1, const ushort* __restrict__ A2,
    const ushort* __restrict__ W0, const ushort* __restrict__ W1, const ushort* __restrict__ W2,
    ushort* __restrict__ Cp, int M, int N)
{
    __shared__ ushort As[128 * 64];
    __shared__ ushort Bs[128 * 64];

    const int t = threadIdx.x, l = t & 63, w = t >> 6;
    const int wm = w >> 1, wn = w & 1;
    const int m0 = blockIdx.y * 128, n0 = blockIdx.x * 128;

    const int srow = l >> 3;
    const int csw  = ((l & 7) ^ (l >> 3)) * 8;
    const int kx0 = ((0 + (l >> 4)) ^ (l & 7)) * 8;
    const int kx1 = ((4 + (l >> 4)) ^ (l & 7)) * 8;

    f32x4 acc[4][4];
#pragma unroll
    for (int i = 0; i < 4; ++i)
#pragma unroll
        for (int j = 0; j < 4; ++j) acc[i][j] = (f32x4){0.f, 0.f, 0.f, 0.f};

    const int total = NP * 16;
    const int per   = total / SK;
    const int s0v   = blockIdx.z * per;
    const int sEnd  = s0v + per;

    for (int s = s0v; s < sEnd; ++s) {
        const int p  = (NP == 1) ? 0 : (s >> 4);
        const int k0 = (s & 15) << 6;
        const ushort* Ap = (p == 0) ? A0 : ((p == 1) ? A1 : A2);
        const ushort* Wp = (p == 0) ? W0 : ((p == 1) ? W1 : W2);
#pragma unroll
        for (int j = 0; j < 4; ++j) {
            const int rb = w * 32 + j * 8;
            gll16(Ap + (size_t)(m0 + rb + srow) * 1024 + k0 + csw, &As[rb * 64]);
            gll16(Wp + (size_t)(n0 + rb + srow) * 1024 + k0 + csw, &Bs[rb * 64]);
        }
        __syncthreads();

        short8 aF[4][2], bF[4][2];
#pragma unroll
        for (int mi = 0; mi < 4; ++mi) {
            const int ro = (wm * 64 + mi * 16 + (l & 15)) * 64;
            aF[mi][0] = *(const short8*)&As[ro + kx0];
            aF[mi][1] = *(const short8*)&As[ro + kx1];
        }
#pragma unroll
        for (int ni = 0; ni < 4; ++ni) {
            const int ro = (wn * 64 + ni * 16 + (l & 15)) * 64;
            bF[ni][0] = *(const short8*)&Bs[ro + kx0];
            bF[ni][1] = *(const short8*)&Bs[ro + kx1];
        }
#pragma unroll
        for (int mi = 0; mi < 4; ++mi)
#pragma unroll
            for (int ni = 0; ni < 4; ++ni) {
                acc[mi][ni] = __builtin_amdgcn_mfma_f32_16x16x32_bf16(
                    aF[mi][0], bF[ni][0], acc[mi][ni], 0, 0, 0);
                acc[mi][ni] = __builtin_amdgcn_mfma_f32_16x16x32_bf16(
                    aF[mi][1], bF[ni][1], acc[mi][ni], 0, 0, 0);
            }
        __syncthreads();
    }

    ushort* Cz = Cp + (size_t)blockIdx.z * M * N;
#pragma unroll
    for (int ni = 0; ni < 4; ++ni) {
        const int col = n0 + wn * 64 + ni * 16 + (l & 15);
#pragma unroll
        for (int mi = 0; mi < 4; ++mi) {
            const int row = m0 + wm * 64 + mi * 16 + ((l >> 4) << 2);
#pragma unroll
            for (int r = 0; r < 4; ++r)
                Cz[(size_t)(row + r) * N + col] = f2bf(acc[mi][ni][r]);
        }
    }
}

// ---------------------------------------------------------------------------
// WIDE GEMM: 256x128 block, 4 waves, PER-WAVE 128x64 (32 MFMA per barrier
// pair — 2x the 128^2 family). R10-proven dbuf + counted vmcnt(6) schedule,
// identical pair-swizzle formulas (row offsets are multiples of 16).
// LDS: A 2x16KB + B 2x8KB = 48 KB. __launch_bounds__(256,2) -> 2 blocks/CU.
// EPI: 2 = attn tanh-reduce -> epart[row*4+bx]; 3 = bf16 split-K partial.
// ---------------------------------------------------------------------------
template <int NP, int SK, int EPI>
__global__ __launch_bounds__(256, 2) void gemm_w(
    const ushort* __restrict__ A0, const ushort* __restrict__ A1, const ushort* __restrict__ A2,
    const ushort* __restrict__ W0, const ushort* __restrict__ W1, const ushort* __restrict__ W2,
    ushort* __restrict__ Cp, int M, int N,
    const float* __restrict__ hq, const float* __restrict__ bv2a,
    const float* __restrict__ Wa2w, float* __restrict__ epart)
{
    __shared__ ushort As[2][256 * 32];   // 2 x 16 KB
    __shared__ ushort Bs[2][128 * 32];   // 2 x 8 KB

    const int t = threadIdx.x, l = t & 63, w = t >> 6;
    const int wm = w >> 1, wn = w & 1;   // per-wave: rows wm*128..+127, cols wn*64..+63

    int bx, by;
    if constexpr (EPI == 2) {
        // XCD-chunked bijective swizzle: nwg = 4*160 = 640 = 8*80
        const int lin = blockIdx.y * gridDim.x + blockIdx.x;
        const int swz = (lin & 7) * 80 + (lin >> 3);
        bx = swz & 3; by = swz >> 2;
    } else { bx = blockIdx.x; by = blockIdx.y; }
    const int m0 = by * 256, n0 = bx * 128;

    const int srow  = l >> 2;
    const int schnk = ((l & 3) ^ ((l >> 3) & 3)) * 8;

    int aoff[8], boff[4];
#pragma unroll
    for (int mi = 0; mi < 8; ++mi)
        aoff[mi] = (wm * 128 + mi * 16 + (l & 15)) * 32 + (((l >> 4) ^ ((l >> 1) & 3)) * 8);
#pragma unroll
    for (int ni = 0; ni < 4; ++ni)
        boff[ni] = (wn * 64 + ni * 16 + (l & 15)) * 32 + (((l >> 4) ^ ((l >> 1) & 3)) * 8);

    f32x4 acc[8][4];
#pragma unroll
    for (int i = 0; i < 8; ++i)
#pragma unroll
        for (int j = 0; j < 4; ++j) acc[i][j] = (f32x4){0.f, 0.f, 0.f, 0.f};

    const int total = NP * 32;           // K-steps of 32
    const int per   = total / SK;
    const int s0v   = blockIdx.z * per;
    const int sEnd  = s0v + per;

    auto stage = [&](int s, int buf) {   // 6 gll16 per thread (4 A + 2 B)
        const int p  = (NP == 1) ? 0 : (s >> 5);
        const int k0 = (s & 31) << 5;
        const ushort* Ap = (p == 0) ? A0 : ((p == 1) ? A1 : A2);
        const ushort* Wp = (p == 0) ? W0 : ((p == 1) ? W1 : W2);
#pragma unroll
        for (int j = 0; j < 4; ++j) {
            const int rb = (w * 4 + j) * 16;
            gll16(Ap + (size_t)(m0 + rb + srow) * 1024 + k0 + schnk, &As[buf][rb * 32]);
        }
#pragma unroll
        for (int j = 0; j < 2; ++j) {
            const int rb = (w * 2 + j) * 16;
            gll16(Wp + (size_t)(n0 + rb + srow) * 1024 + k0 + schnk, &Bs[buf][rb * 32]);
        }
    };

    stage(s0v, 0);
    int cur = 0;
    for (int s = s0v; s < sEnd; ++s) {
        const bool pf = (s + 1 < sEnd);
        if (pf) {
            stage(s + 1, cur ^ 1);        // up to 12 outstanding
            asm volatile("s_waitcnt vmcnt(6)" ::: "memory");   // retire tile s
        } else {
            asm volatile("s_waitcnt vmcnt(0)" ::: "memory");
        }
        __builtin_amdgcn_s_barrier();     // buffer cur resident for all waves
        asm volatile("" ::: "memory");

        short8 aF[8], bF[4];
#pragma unroll
        for (int mi = 0; mi < 8; ++mi) aF[mi] = *(const short8*)&As[cur][aoff[mi]];
#pragma unroll
        for (int ni = 0; ni < 4; ++ni) bF[ni] = *(const short8*)&Bs[cur][boff[ni]];
#pragma unroll
        for (int mi = 0; mi < 8; ++mi)
#pragma unroll
            for (int ni = 0; ni < 4; ++ni)
                acc[mi][ni] = __builtin_amdgcn_mfma_f32_16x16x32_bf16(
                    aF[mi], bF[ni], acc[mi][ni], 0, 0, 0);

        asm volatile("" ::: "memory");
        __builtin_amdgcn_s_barrier();     // all waves done reading cur
        asm volatile("" ::: "memory");
        cur ^= 1;
    }

    if constexpr (EPI == 3) {
        ushort* Cz = Cp + (size_t)blockIdx.z * M * N;
#pragma unroll
        for (int ni = 0; ni < 4; ++ni) {
            const int col = n0 + wn * 64 + ni * 16 + (l & 15);
#pragma unroll
            for (int mi = 0; mi < 8; ++mi) {
                const int row = m0 + wm * 128 + mi * 16 + ((l >> 4) << 2);
#pragma unroll
                for (int r = 0; r < 4; ++r)
                    Cz[(size_t)(row + r) * N + col] = f2bf(acc[mi][ni][r]);
            }
        }
    } else if constexpr (EPI == 2) {
        float* red = (float*)&As[0][0];    // [256][2]
        float wa[4], bv[4];
        int coln[4];
#pragma unroll
        for (int ni = 0; ni < 4; ++ni) {
            coln[ni] = n0 + wn * 64 + ni * 16 + (l & 15);
            wa[ni] = Wa2w[coln[ni]];
            bv[ni] = bv2a[coln[ni]];
        }
#pragma unroll
        for (int mi = 0; mi < 8; ++mi) {
            const int rowl = wm * 128 + mi * 16 + ((l >> 4) << 2);
#pragma unroll
            for (int r = 0; r < 4; ++r) {
                const int row = m0 + rowl + r;
                const int b = row / LL;
                float v = 0.f;
#pragma unroll
                for (int ni = 0; ni < 4; ++ni) {
                    float x = acc[mi][ni][r] + hq[(size_t)b * 512 + coln[ni]] + bv[ni];
                    v += ftanh(x) * wa[ni];
                }
                v += __shfl_xor(v, 1);
                v += __shfl_xor(v, 2);
                v += __shfl_xor(v, 4);
                v += __shfl_xor(v, 8);
                if ((l & 15) == 0) red[(rowl + r) * 2 + wn] = v;
            }
        }
        __syncthreads();
        if (t < 256)
            epart[(size_t)(m0 + t) * 4 + bx] = red[t * 2] + red[t * 2 + 1];
    }
}

// ---------------------------------------------------------------------------
__global__ __launch_bounds__(256) void reduce_hq_b_kernel(
    const ushort* __restrict__ part, const float* __restrict__ bias, float* __restrict__ hq)
{
    const int i = blockIdx.x * 256 + threadIdx.x;   // < 1024*512
    float s = bias[i & 511];
#pragma unroll
    for (int z = 0; z < 8; ++z) s += bf2f(part[(size_t)z * 524288 + i]);
    hq[i] = s;
}

__global__ __launch_bounds__(256) void reduce_gate_b_kernel(
    const ushort* __restrict__ part, const float* __restrict__ bias,
    const float* __restrict__ pos, ushort* __restrict__ gpb)
{
    const int i = blockIdx.x * 256 + threadIdx.x;   // < 1024*1024
    float s = bias[i & 1023];
#pragma unroll
    for (int z = 0; z < 4; ++z) s += bf2f(part[(size_t)z * 1048576 + i]);
    const float g = fmaxf(s, 0.f);
    gpb[i] = f2bf(g * pos[i] + pos[i]);
}

// ---------------------------------------------------------------------------
__global__ __launch_bounds__(256) void softmax_af_kernel(
    const float* __restrict__ epart, const ushort* __restrict__ Vb,
    const float* __restrict__ ba2w, ushort* __restrict__ afb)
{
    const int b = blockIdx.x;
    const int tid = threadIdx.x;
    __shared__ float e_raw[LL];
    __shared__ float e_exp[LL];

    if (tid < LL) {
        const float* ep = &epart[(size_t)(b * LL + tid) * 4];
        float e = ba2w[0];
#pragma unroll
        for (int c = 0; c < 4; ++c) e += ep[c];
        e_raw[tid] = e;
    }
    __syncthreads();
    float mx = -1e30f;
#pragma unroll
    for (int ll = 0; ll < LL; ++ll) mx = fmaxf(mx, e_raw[ll]);
    if (tid < LL) e_exp[tid] = __expf(e_raw[tid] - mx);
    __syncthreads();
    float sum = 0.f;
#pragma unroll
    for (int ll = 0; ll < LL; ++ll) sum += e_exp[ll];
    const float inv = 1.f / sum;

    const int r4 = tid * 4;
    const ushort* vp = &Vb[(size_t)b * LL * RR + r4];
    float a0 = 0.f, a1 = 0.f, a2 = 0.f, a3 = 0.f;
#pragma unroll 8
    for (int ll = 0; ll < LL; ++ll) {
        ushort4 v = *(const ushort4*)&vp[(size_t)ll * RR];
        const float wgt = e_exp[ll];
        a0 += wgt * bf2f(v.x); a1 += wgt * bf2f(v.y);
        a2 += wgt * bf2f(v.z); a3 += wgt * bf2f(v.w);
    }
    ushort* op = &afb[(size_t)b * RR + r4];
    op[0] = f2bf(a0 * inv); op[1] = f2bf(a1 * inv);
    op[2] = f2bf(a2 * inv); op[3] = f2bf(a3 * inv);
}

// ---------------------------------------------------------------------------
__global__ __launch_bounds__(256) void lstm_finishb_kernel(
    const ushort* __restrict__ part,
    const float* __restrict__ bi, const float* __restrict__ ba, const float* __restrict__ bh,
    const float* __restrict__ c_in, const float* __restrict__ h_in, const float* __restrict__ mask,
    float* __restrict__ h_out, float* __restrict__ h_out2,
    float* __restrict__ c_out, ushort* __restrict__ h_bf)
{
    const int i = blockIdx.x * 256 + threadIdx.x;  // [0, B*R)
    const int b = i >> 10;
    const int r = i & 1023;
    float sg[4];
#pragma unroll
    for (int g = 0; g < 4; ++g) {
        const int gr = g * 1024 + r;
        float s = bi[gr] + ba[gr] + bh[gr];
#pragma unroll
        for (int z = 0; z < 4; ++z)
            s += bf2f(part[(size_t)z * 4194304 + (size_t)b * 4096 + gr]);
        sg[g] = s;
    }
    const float ig = fsigmoid(sg[0]);
    const float fg = fsigmoid(sg[1]);
    const float og = fsigmoid(sg[2]);
    const float gt = ftanh(sg[3]);
    const float m = mask[b];
    const float c = c_in[i];
    float cn = fg * c + ig * gt;
    cn = cn * m + c * (1.f - m);
    const float h = h_in[i];
    float hn = og * ftanh(cn);
    hn = hn * m + h * (1.f - m);
    h_out[i] = hn;
    if (h_out2) h_out2[i] = hn;
    c_out[i] = cn;
    if (h_bf) h_bf[i] = f2bf(hn);
}

extern "C" void kernel_launch(void* const* d_in, const int* in_sizes, int n_in,
                              void* d_out, int out_size, void* d_ws, size_t ws_size,
                              hipStream_t stream) {
    const float* xt   = (const float*)d_in[0];
    const float* mask = (const float*)d_in[1];
    const float* V    = (const float*)d_in[2];
    const float* pos  = (const float*)d_in[3];
    const float* h1   = (const float*)d_in[4];
    const float* c1   = (const float*)d_in[5];
    const float* h2   = (const float*)d_in[6];
    const float* c2   = (const float*)d_in[7];
    const float* Wg   = (const float*)d_in[8];
    const float* bg   = (const float*)d_in[9];
    const float* Wi1  = (const float*)d_in[10];
    const float* bi1  = (const float*)d_in[11];
    const float* Wa1  = (const float*)d_in[12];
    const float* ba1  = (const float*)d_in[13];
    const float* Wh1  = (const float*)d_in[14];
    const float* bh1  = (const float*)d_in[15];
    const float* Wi2  = (const float*)d_in[16];
    const float* bi2  = (const float*)d_in[17];
    const float* Wa2  = (const float*)d_in[18];
    const float* ba2  = (const float*)d_in[19];
    const float* Wh2  = (const float*)d_in[20];
    const float* bh2  = (const float*)d_in[21];
    const float* Wv2a = (const float*)d_in[22];
    const float* bv2a = (const float*)d_in[23];
    const float* Wh2a = (const float*)d_in[24];
    const float* bh2a = (const float*)d_in[25];
    const float* Wa2w = (const float*)d_in[26];
    const float* ba2w = (const float*)d_in[27];

    float* out = (float*)d_out;
    float* out2  = out;
    float* out1  = out + (size_t)BB * RR;
    float* c1n   = out + 2 * (size_t)BB * RR;
    float* out2b = out + 3 * (size_t)BB * RR;
    float* c2n   = out + 4 * (size_t)BB * RR;

    // ---- workspace ----
    ushort* wsu = (ushort*)d_ws;
    size_t o = 0;
    ushort* Vb     = wsu + o; o += (size_t)40960 * 1024;   // 84 MB
    ushort* Wh2aT0 = wsu + o; o += (size_t)512 * 1024;
    ushort* Wh2aT1 = wsu + o; o += (size_t)512 * 1024;
    ushort* WgT    = wsu + o; o += (size_t)1024 * 1024;
    ushort* Wv2aT  = wsu + o; o += (size_t)512 * 1024;
    ushort* Wi1T   = wsu + o; o += (size_t)4096 * 1024;
    ushort* Wa1T   = wsu + o; o += (size_t)4096 * 1024;
    ushort* Wh1T   = wsu + o; o += (size_t)4096 * 1024;
    ushort* Wi2T   = wsu + o; o += (size_t)4096 * 1024;
    ushort* Wa2T   = wsu + o; o += (size_t)4096 * 1024;
    ushort* Wh2T   = wsu + o; o += (size_t)4096 * 1024;
    ushort* xtb    = wsu + o; o += (size_t)1024 * 1024;
    ushort* h1b    = wsu + o; o += (size_t)1024 * 1024;
    ushort* h2b    = wsu + o; o += (size_t)1024 * 1024;
    ushort* gpb    = wsu + o; o += (size_t)1024 * 1024;
    ushort* afb    = wsu + o; o += (size_t)1024 * 1024;
    ushort* out1b  = wsu + o; o += (size_t)1024 * 1024;
    ushort* partSb = wsu + o; o += (size_t)8 * 1024 * 512; // hq x8 / gate x4 bf16 partials
    float* wsf    = (float*)(wsu + o);
    float* hqf    = wsf;                   // 524288
    float* epart  = hqf + 524288;          // 40960*4
    // LSTM bf16 partials (4 x 1024 x 4096 ushort = 32 MB) alias Vb (dead after softmax_af)
    ushort* partKb = Vb;

    const dim3 blk(256);

    // ---- conversion / transpose passes ----
    conv_bf16_kernel<<<dim3(20480), blk, 0, stream>>>(V, Vb, 5242880);
    {
        CP3 p; p.in[0] = xt; p.in[1] = h1; p.in[2] = h2;
        p.out[0] = xtb; p.out[1] = h1b; p.out[2] = h2b;
        conv_bf16_batch3_kernel<<<dim3(512, 3), blk, 0, stream>>>(p, 131072);
    }
    {
        TP6 p;
        p.in[0] = Wi1; p.in[1] = Wa1; p.in[2] = Wh1;
        p.in[3] = Wi2; p.in[4] = Wa2; p.in[5] = Wh2;
        p.out[0] = Wi1T; p.out[1] = Wa1T; p.out[2] = Wh1T;
        p.out[3] = Wi2T; p.out[4] = Wa2T; p.out[5] = Wh2T;
        for (int z = 0; z < 6; ++z) p.N[z] = 4096;
        transpose_conv_kernel<<<dim3(64, 16, 6), blk, 0, stream>>>(p);
    }
    {
        TP6 p;
        p.in[0] = Wh2a; p.in[1] = Wh2a + (size_t)1024 * 512;
        p.in[2] = Wg;   p.in[3] = Wv2a;
        p.out[0] = Wh2aT0; p.out[1] = Wh2aT1; p.out[2] = WgT; p.out[3] = Wv2aT;
        p.N[0] = 512; p.N[1] = 512; p.N[2] = 1024; p.N[3] = 512;
        p.in[4] = nullptr; p.in[5] = nullptr; p.out[4] = nullptr; p.out[5] = nullptr;
        p.N[4] = 0; p.N[5] = 0;
        transpose_conv_kernel<<<dim3(16, 16, 4), blk, 0, stream>>>(p);
    }

    // ---- hq = [h1,h2] @ Wh2a (split-K x8, bf16 partials) + bias reduce ----
    gemm_gl<2, 8><<<dim3(4, 8, 8), blk, 0, stream>>>(
        h1b, h2b, nullptr, Wh2aT0, Wh2aT1, nullptr, partSb, 1024, 512);
    reduce_hq_b_kernel<<<dim3(2048), blk, 0, stream>>>(partSb, bh2a, hqf);

    // ---- gate: xt @ Wg (split-K x4, bf16 partials), relu*pos+pos -> bf16 ----
    gemm_gl<1, 4><<<dim3(8, 8, 4), blk, 0, stream>>>(
        xtb, nullptr, nullptr, WgT, nullptr, nullptr, partSb, 1024, 1024);
    reduce_gate_b_kernel<<<dim3(4096), blk, 0, stream>>>(partSb, bg, pos, gpb);

    // ---- attention scores: wide dbuf Vb @ Wv2a, fused tanh-reduce ----
    gemm_w<1, 1, 2><<<dim3(4, 160), blk, 0, stream>>>(
        Vb, nullptr, nullptr, Wv2aT, nullptr, nullptr,
        nullptr, 40960, 512, hqf, bv2a, Wa2w, epart);
    softmax_af_kernel<<<dim3(BB), blk, 0, stream>>>(epart, Vb, ba2w, afb);

    // ---- LSTM layer 1 (wide, split-K x4 over fused K = xt|gp|h1) ----
    gemm_w<3, 4, 3><<<dim3(32, 4, 4), blk, 0, stream>>>(
        xtb, gpb, h1b, Wi1T, Wa1T, Wh1T,
        partKb, 1024, 4096, nullptr, nullptr, nullptr, nullptr);
    lstm_finishb_kernel<<<dim3(4096), blk, 0, stream>>>(
        partKb, bi1, ba1, bh1, c1, h1, mask, out1, nullptr, c1n, out1b);

    // ---- LSTM layer 2 (wide, split-K x4 over fused K = out1|af|h2) ----
    gemm_w<3, 4, 3><<<dim3(32, 4, 4), blk, 0, stream>>>(
        out1b, afb, h2b, Wi2T, Wa2T, Wh2T,
        partKb, 1024, 4096, nullptr, nullptr, nullptr, nullptr);
    lstm_finishb_kernel<<<dim3(4096), blk, 0, stream>>>(
        partKb, bi2, ba2, bh2, c2, h2, mask, out2, out2b, c2n, nullptr);
}

// Round 14
// 327.656 us; speedup vs baseline: 1.2538x; 1.2538x over previous
//
#include <hip/hip_runtime.h>
#include <math.h>

#define BB 1024
#define LL 40
#define RR 1024

using short8 = __attribute__((ext_vector_type(8))) short;
using us8    = __attribute__((ext_vector_type(8))) unsigned short;
using f32x4  = __attribute__((ext_vector_type(4))) float;

__device__ __forceinline__ ushort f2bf(float f) {
    union { float f; unsigned u; } a; a.f = f;
    unsigned r = a.u + 0x7fffu + ((a.u >> 16) & 1u);  // RNE
    return (ushort)(r >> 16);
}
__device__ __forceinline__ float bf2f(ushort u) {
    union { unsigned u; float f; } a; a.u = ((unsigned)u) << 16;
    return a.f;
}
__device__ __forceinline__ float ftanh(float x) {
    float cx = fminf(fmaxf(x, -15.f), 15.f);
    float e = __expf(2.f * cx);
    return (e - 1.f) / (e + 1.f);
}
__device__ __forceinline__ float fsigmoid(float x) {
    float cx = fminf(fmaxf(x, -30.f), 30.f);
    return 1.f / (1.f + __expf(-cx));
}

__device__ __forceinline__ void gll16(const ushort* g, ushort* l) {
    __builtin_amdgcn_global_load_lds(
        (const __attribute__((address_space(1))) void*)g,
        (__attribute__((address_space(3))) void*)l,
        16, 0, 0);
}

// ---------------------------------------------------------------------------
__global__ __launch_bounds__(256) void conv_bf16_kernel(
    const float* __restrict__ src, ushort* __restrict__ dst, int n8)
{
    const int i = blockIdx.x * 256 + threadIdx.x;
    if (i >= n8) return;
    const float4* s4 = (const float4*)(src + (size_t)i * 8);
    float4 x = s4[0], y = s4[1];
    us8 v;
    v[0] = f2bf(x.x); v[1] = f2bf(x.y); v[2] = f2bf(x.z); v[3] = f2bf(x.w);
    v[4] = f2bf(y.x); v[5] = f2bf(y.y); v[6] = f2bf(y.z); v[7] = f2bf(y.w);
    ((us8*)dst)[i] = v;
}

struct CP3 { const float* in[3]; ushort* out[3]; };
__global__ __launch_bounds__(256) void conv_bf16_batch3_kernel(CP3 p, int n8)
{
    const int z = blockIdx.y;
    const int i = blockIdx.x * 256 + threadIdx.x;
    if (i >= n8) return;
    const float4* s4 = (const float4*)(p.in[z] + (size_t)i * 8);
    float4 x = s4[0], y = s4[1];
    us8 v;
    v[0] = f2bf(x.x); v[1] = f2bf(x.y); v[2] = f2bf(x.z); v[3] = f2bf(x.w);
    v[4] = f2bf(y.x); v[5] = f2bf(y.y); v[6] = f2bf(y.z); v[7] = f2bf(y.w);
    ((us8*)p.out[z])[i] = v;
}

struct TP6 { const float* in[6]; ushort* out[6]; int N[6]; };
__global__ __launch_bounds__(256) void transpose_conv_kernel(TP6 p)
{
    const int z = blockIdx.z;
    const int Nn = p.N[z];
    const int n0 = blockIdx.x * 64;
    if (n0 >= Nn) return;
    const int k0 = blockIdx.y * 64;
    const float* in = p.in[z];
    ushort* out = p.out[z];

    __shared__ float tile[64][65];
    const int t = threadIdx.x;
    const int tx = t & 63, ty = t >> 6;
#pragma unroll
    for (int r = 0; r < 16; ++r) {
        const int row = ty * 16 + r;
        tile[row][tx] = in[(size_t)(k0 + row) * Nn + n0 + tx];
    }
    __syncthreads();
    const int n = t >> 2, kq = t & 3;
    us8 v0, v1;
#pragma unroll
    for (int j = 0; j < 8; ++j) v0[j] = f2bf(tile[kq * 16 + j][n]);
#pragma unroll
    for (int j = 0; j < 8; ++j) v1[j] = f2bf(tile[kq * 16 + 8 + j][n]);
    ushort* op = out + (size_t)(n0 + n) * 1024 + k0 + kq * 16;
    *(us8*)op = v0;
    *((us8*)op + 1) = v1;
}

// ---------------------------------------------------------------------------
// R8-proven 128x128 BK=64 4-wave GEMM (single-buffer, XOR swizzle, 0 bank
// conflicts). For hq/gate/LSTM. bf16 split-K partial store.
// ---------------------------------------------------------------------------
template <int NP, int SK>
__global__ __launch_bounds__(256) void gemm_gl(
    const ushort* __restrict__ A0, const ushort* __restrict__ A1, const ushort* __restrict__ A2,
    const ushort* __restrict__ W0, const ushort* __restrict__ W1, const ushort* __restrict__ W2,
    ushort* __restrict__ Cp, int M, int N)
{
    __shared__ ushort As[128 * 64];
    __shared__ ushort Bs[128 * 64];

    const int t = threadIdx.x, l = t & 63, w = t >> 6;
    const int wm = w >> 1, wn = w & 1;
    const int m0 = blockIdx.y * 128, n0 = blockIdx.x * 128;

    const int srow = l >> 3;
    const int csw  = ((l & 7) ^ (l >> 3)) * 8;
    const int kx0 = ((0 + (l >> 4)) ^ (l & 7)) * 8;
    const int kx1 = ((4 + (l >> 4)) ^ (l & 7)) * 8;

    f32x4 acc[4][4];
#pragma unroll
    for (int i = 0; i < 4; ++i)
#pragma unroll
        for (int j = 0; j < 4; ++j) acc[i][j] = (f32x4){0.f, 0.f, 0.f, 0.f};

    const int total = NP * 16;
    const int per   = total / SK;
    const int s0v   = blockIdx.z * per;
    const int sEnd  = s0v + per;

    for (int s = s0v; s < sEnd; ++s) {
        const int p  = (NP == 1) ? 0 : (s >> 4);
        const int k0 = (s & 15) << 6;
        const ushort* Ap = (p == 0) ? A0 : ((p == 1) ? A1 : A2);
        const ushort* Wp = (p == 0) ? W0 : ((p == 1) ? W1 : W2);
#pragma unroll
        for (int j = 0; j < 4; ++j) {
            const int rb = w * 32 + j * 8;
            gll16(Ap + (size_t)(m0 + rb + srow) * 1024 + k0 + csw, &As[rb * 64]);
            gll16(Wp + (size_t)(n0 + rb + srow) * 1024 + k0 + csw, &Bs[rb * 64]);
        }
        __syncthreads();

        short8 aF[4][2], bF[4][2];
#pragma unroll
        for (int mi = 0; mi < 4; ++mi) {
            const int ro = (wm * 64 + mi * 16 + (l & 15)) * 64;
            aF[mi][0] = *(const short8*)&As[ro + kx0];
            aF[mi][1] = *(const short8*)&As[ro + kx1];
        }
#pragma unroll
        for (int ni = 0; ni < 4; ++ni) {
            const int ro = (wn * 64 + ni * 16 + (l & 15)) * 64;
            bF[ni][0] = *(const short8*)&Bs[ro + kx0];
            bF[ni][1] = *(const short8*)&Bs[ro + kx1];
        }
#pragma unroll
        for (int mi = 0; mi < 4; ++mi)
#pragma unroll
            for (int ni = 0; ni < 4; ++ni) {
                acc[mi][ni] = __builtin_amdgcn_mfma_f32_16x16x32_bf16(
                    aF[mi][0], bF[ni][0], acc[mi][ni], 0, 0, 0);
                acc[mi][ni] = __builtin_amdgcn_mfma_f32_16x16x32_bf16(
                    aF[mi][1], bF[ni][1], acc[mi][ni], 0, 0, 0);
            }
        __syncthreads();
    }

    ushort* Cz = Cp + (size_t)blockIdx.z * M * N;
#pragma unroll
    for (int ni = 0; ni < 4; ++ni) {
        const int col = n0 + wn * 64 + ni * 16 + (l & 15);
#pragma unroll
        for (int mi = 0; mi < 4; ++mi) {
            const int row = m0 + wm * 64 + mi * 16 + ((l >> 4) << 2);
#pragma unroll
            for (int r = 0; r < 4; ++r)
                Cz[(size_t)(row + r) * N + col] = f2bf(acc[mi][ni][r]);
        }
    }
}

// ---------------------------------------------------------------------------
// R10/R12-proven attn GEMM: 128x128 BK=32 dbuf, counted vmcnt(4) prefetch,
// pair-swizzle LDS (0 bank conflicts). Fused tanh*Wa2w epilogue.
// R14 micro-opt: incremental stage pointers (+=32/step) and cur = s&1 with
// #pragma unroll 2 so buffer bases become compile-time immediates.
// ---------------------------------------------------------------------------
__global__ __launch_bounds__(256) void attn_db(
    const ushort* __restrict__ A0, const ushort* __restrict__ W0,
    const float* __restrict__ hq, const float* __restrict__ bv2a,
    const float* __restrict__ Wa2w, float* __restrict__ epart)
{
    __shared__ ushort As[2][128 * 32];   // 2 x 8 KB
    __shared__ ushort Bs[2][128 * 32];   // 2 x 8 KB

    const int t = threadIdx.x, l = t & 63, w = t >> 6;
    const int wm = w >> 1, wn = w & 1;

    // XCD-chunked bijective swizzle: nwg = 4*320 = 1280 = 8*160
    const int lin = blockIdx.y * gridDim.x + blockIdx.x;
    const int swz = (lin & 7) * 160 + (lin >> 3);
    const int bx = swz & 3, by = swz >> 2;
    const int m0 = by * 128, n0 = bx * 128;

    const int srow  = l >> 2;
    const int schnk = ((l & 3) ^ ((l >> 3) & 3)) * 8;

    int aoff[4], boff[4];
#pragma unroll
    for (int mi = 0; mi < 4; ++mi)
        aoff[mi] = (wm * 64 + mi * 16 + (l & 15)) * 32 + (((l >> 4) ^ ((l >> 1) & 3)) * 8);
#pragma unroll
    for (int ni = 0; ni < 4; ++ni)
        boff[ni] = (wn * 64 + ni * 16 + (l & 15)) * 32 + (((l >> 4) ^ ((l >> 1) & 3)) * 8);

    f32x4 acc[4][4];
#pragma unroll
    for (int i = 0; i < 4; ++i)
#pragma unroll
        for (int j = 0; j < 4; ++j) acc[i][j] = (f32x4){0.f, 0.f, 0.f, 0.f};

    // incremental staging pointers: advance 32 elems (one K-step) per stage
    const ushort* pA0 = A0 + (size_t)(m0 + w * 16 + srow) * 1024 + schnk;
    const ushort* pA1 = A0 + (size_t)(m0 + 64 + w * 16 + srow) * 1024 + schnk;
    const ushort* pB0 = W0 + (size_t)(n0 + w * 16 + srow) * 1024 + schnk;
    const ushort* pB1 = W0 + (size_t)(n0 + 64 + w * 16 + srow) * 1024 + schnk;
    const int rb0 = (w * 16) * 32, rb1 = (64 + w * 16) * 32;

    auto stage = [&](int buf) {   // 4 gll16 per thread; pointers auto-advance
        gll16(pA0, &As[buf][rb0]);
        gll16(pA1, &As[buf][rb1]);
        gll16(pB0, &Bs[buf][rb0]);
        gll16(pB1, &Bs[buf][rb1]);
        pA0 += 32; pA1 += 32; pB0 += 32; pB1 += 32;
    };

    constexpr int NS = 32;               // K-steps of 32 (K = 1024)
    stage(0);
#pragma unroll 2
    for (int s = 0; s < NS; ++s) {
        const int cur = s & 1;           // compile-time per unrolled copy
        const bool pf = (s + 1 < NS);
        if (pf) {
            stage(cur ^ 1);               // up to 8 outstanding
            asm volatile("s_waitcnt vmcnt(4)" ::: "memory");   // retire tile s
        } else {
            asm volatile("s_waitcnt vmcnt(0)" ::: "memory");
        }
        __builtin_amdgcn_s_barrier();     // buffer cur resident for all waves
        asm volatile("" ::: "memory");

        short8 aF[4], bF[4];
#pragma unroll
        for (int mi = 0; mi < 4; ++mi) aF[mi] = *(const short8*)&As[cur][aoff[mi]];
#pragma unroll
        for (int ni = 0; ni < 4; ++ni) bF[ni] = *(const short8*)&Bs[cur][boff[ni]];
#pragma unroll
        for (int mi = 0; mi < 4; ++mi)
#pragma unroll
            for (int ni = 0; ni < 4; ++ni)
                acc[mi][ni] = __builtin_amdgcn_mfma_f32_16x16x32_bf16(
                    aF[mi], bF[ni], acc[mi][ni], 0, 0, 0);

        asm volatile("" ::: "memory");
        __builtin_amdgcn_s_barrier();     // all waves done reading cur
        asm volatile("" ::: "memory");
    }

    // ---- fused epilogue: tanh(acc + hq + bv2a) * Wa2w reduced over 128 cols
    float* red = (float*)&As[0][0];       // [128][2]
    float wa[4], bv[4];
    int coln[4];
#pragma unroll
    for (int ni = 0; ni < 4; ++ni) {
        coln[ni] = n0 + wn * 64 + ni * 16 + (l & 15);
        wa[ni] = Wa2w[coln[ni]];
        bv[ni] = bv2a[coln[ni]];
    }
#pragma unroll
    for (int mi = 0; mi < 4; ++mi) {
        const int rowl = wm * 64 + mi * 16 + ((l >> 4) << 2);
#pragma unroll
        for (int r = 0; r < 4; ++r) {
            const int row = m0 + rowl + r;
            const int b = row / LL;
            float v = 0.f;
#pragma unroll
            for (int ni = 0; ni < 4; ++ni) {
                float x = acc[mi][ni][r] + hq[(size_t)b * 512 + coln[ni]] + bv[ni];
                v += ftanh(x) * wa[ni];
            }
            v += __shfl_xor(v, 1);
            v += __shfl_xor(v, 2);
            v += __shfl_xor(v, 4);
            v += __shfl_xor(v, 8);
            if ((l & 15) == 0) red[(rowl + r) * 2 + wn] = v;
        }
    }
    __syncthreads();
    if (t < 128)
        epart[(size_t)(m0 + t) * 4 + bx] = red[t * 2] + red[t * 2 + 1];
}

// ---------------------------------------------------------------------------
__global__ __launch_bounds__(256) void reduce_hq_b_kernel(
    const ushort* __restrict__ part, const float* __restrict__ bias, float* __restrict__ hq)
{
    const int i = blockIdx.x * 256 + threadIdx.x;   // < 1024*512
    float s = bias[i & 511];
#pragma unroll
    for (int z = 0; z < 8; ++z) s += bf2f(part[(size_t)z * 524288 + i]);
    hq[i] = s;
}

__global__ __launch_bounds__(256) void reduce_gate_b_kernel(
    const ushort* __restrict__ part, const float* __restrict__ bias,
    const float* __restrict__ pos, ushort* __restrict__ gpb)
{
    const int i = blockIdx.x * 256 + threadIdx.x;   // < 1024*1024
    float s = bias[i & 1023];
#pragma unroll
    for (int z = 0; z < 4; ++z) s += bf2f(part[(size_t)z * 1048576 + i]);
    const float g = fmaxf(s, 0.f);
    gpb[i] = f2bf(g * pos[i] + pos[i]);
}

// ---------------------------------------------------------------------------
__global__ __launch_bounds__(256) void softmax_af_kernel(
    const float* __restrict__ epart, const ushort* __restrict__ Vb,
    const float* __restrict__ ba2w, ushort* __restrict__ afb)
{
    const int b = blockIdx.x;
    const int tid = threadIdx.x;
    __shared__ float e_raw[LL];
    __shared__ float e_exp[LL];

    if (tid < LL) {
        const float* ep = &epart[(size_t)(b * LL + tid) * 4];
        float e = ba2w[0];
#pragma unroll
        for (int c = 0; c < 4; ++c) e += ep[c];
        e_raw[tid] = e;
    }
    __syncthreads();
    float mx = -1e30f;
#pragma unroll
    for (int ll = 0; ll < LL; ++ll) mx = fmaxf(mx, e_raw[ll]);
    if (tid < LL) e_exp[tid] = __expf(e_raw[tid] - mx);
    __syncthreads();
    float sum = 0.f;
#pragma unroll
    for (int ll = 0; ll < LL; ++ll) sum += e_exp[ll];
    const float inv = 1.f / sum;

    const int r4 = tid * 4;
    const ushort* vp = &Vb[(size_t)b * LL * RR + r4];
    float a0 = 0.f, a1 = 0.f, a2 = 0.f, a3 = 0.f;
#pragma unroll 8
    for (int ll = 0; ll < LL; ++ll) {
        ushort4 v = *(const ushort4*)&vp[(size_t)ll * RR];
        const float wgt = e_exp[ll];
        a0 += wgt * bf2f(v.x); a1 += wgt * bf2f(v.y);
        a2 += wgt * bf2f(v.z); a3 += wgt * bf2f(v.w);
    }
    ushort* op = &afb[(size_t)b * RR + r4];
    op[0] = f2bf(a0 * inv); op[1] = f2bf(a1 * inv);
    op[2] = f2bf(a2 * inv); op[3] = f2bf(a3 * inv);
}

// ---------------------------------------------------------------------------
__global__ __launch_bounds__(256) void lstm_finishb_kernel(
    const ushort* __restrict__ part,
    const float* __restrict__ bi, const float* __restrict__ ba, const float* __restrict__ bh,
    const float* __restrict__ c_in, const float* __restrict__ h_in, const float* __restrict__ mask,
    float* __restrict__ h_out, float* __restrict__ h_out2,
    float* __restrict__ c_out, ushort* __restrict__ h_bf)
{
    const int i = blockIdx.x * 256 + threadIdx.x;  // [0, B*R)
    const int b = i >> 10;
    const int r = i & 1023;
    float sg[4];
#pragma unroll
    for (int g = 0; g < 4; ++g) {
        const int gr = g * 1024 + r;
        float s = bi[gr] + ba[gr] + bh[gr];
#pragma unroll
        for (int z = 0; z < 4; ++z)
            s += bf2f(part[(size_t)z * 4194304 + (size_t)b * 4096 + gr]);
        sg[g] = s;
    }
    const float ig = fsigmoid(sg[0]);
    const float fg = fsigmoid(sg[1]);
    const float og = fsigmoid(sg[2]);
    const float gt = ftanh(sg[3]);
    const float m = mask[b];
    const float c = c_in[i];
    float cn = fg * c + ig * gt;
    cn = cn * m + c * (1.f - m);
    const float h = h_in[i];
    float hn = og * ftanh(cn);
    hn = hn * m + h * (1.f - m);
    h_out[i] = hn;
    if (h_out2) h_out2[i] = hn;
    c_out[i] = cn;
    if (h_bf) h_bf[i] = f2bf(hn);
}

extern "C" void kernel_launch(void* const* d_in, const int* in_sizes, int n_in,
                              void* d_out, int out_size, void* d_ws, size_t ws_size,
                              hipStream_t stream) {
    const float* xt   = (const float*)d_in[0];
    const float* mask = (const float*)d_in[1];
    const float* V    = (const float*)d_in[2];
    const float* pos  = (const float*)d_in[3];
    const float* h1   = (const float*)d_in[4];
    const float* c1   = (const float*)d_in[5];
    const float* h2   = (const float*)d_in[6];
    const float* c2   = (const float*)d_in[7];
    const float* Wg   = (const float*)d_in[8];
    const float* bg   = (const float*)d_in[9];
    const float* Wi1  = (const float*)d_in[10];
    const float* bi1  = (const float*)d_in[11];
    const float* Wa1  = (const float*)d_in[12];
    const float* ba1  = (const float*)d_in[13];
    const float* Wh1  = (const float*)d_in[14];
    const float* bh1  = (const float*)d_in[15];
    const float* Wi2  = (const float*)d_in[16];
    const float* bi2  = (const float*)d_in[17];
    const float* Wa2  = (const float*)d_in[18];
    const float* ba2  = (const float*)d_in[19];
    const float* Wh2  = (const float*)d_in[20];
    const float* bh2  = (const float*)d_in[21];
    const float* Wv2a = (const float*)d_in[22];
    const float* bv2a = (const float*)d_in[23];
    const float* Wh2a = (const float*)d_in[24];
    const float* bh2a = (const float*)d_in[25];
    const float* Wa2w = (const float*)d_in[26];
    const float* ba2w = (const float*)d_in[27];

    float* out = (float*)d_out;
    float* out2  = out;
    float* out1  = out + (size_t)BB * RR;
    float* c1n   = out + 2 * (size_t)BB * RR;
    float* out2b = out + 3 * (size_t)BB * RR;
    float* c2n   = out + 4 * (size_t)BB * RR;

    // ---- workspace ----
    ushort* wsu = (ushort*)d_ws;
    size_t o = 0;
    ushort* Vb     = wsu + o; o += (size_t)40960 * 1024;   // 84 MB
    ushort* Wh2aT0 = wsu + o; o += (size_t)512 * 1024;
    ushort* Wh2aT1 = wsu + o; o += (size_t)512 * 1024;
    ushort* WgT    = wsu + o; o += (size_t)1024 * 1024;
    ushort* Wv2aT  = wsu + o; o += (size_t)512 * 1024;
    ushort* Wi1T   = wsu + o; o += (size_t)4096 * 1024;
    ushort* Wa1T   = wsu + o; o += (size_t)4096 * 1024;
    ushort* Wh1T   = wsu + o; o += (size_t)4096 * 1024;
    ushort* Wi2T   = wsu + o; o += (size_t)4096 * 1024;
    ushort* Wa2T   = wsu + o; o += (size_t)4096 * 1024;
    ushort* Wh2T   = wsu + o; o += (size_t)4096 * 1024;
    ushort* xtb    = wsu + o; o += (size_t)1024 * 1024;
    ushort* h1b    = wsu + o; o += (size_t)1024 * 1024;
    ushort* h2b    = wsu + o; o += (size_t)1024 * 1024;
    ushort* gpb    = wsu + o; o += (size_t)1024 * 1024;
    ushort* afb    = wsu + o; o += (size_t)1024 * 1024;
    ushort* out1b  = wsu + o; o += (size_t)1024 * 1024;
    ushort* partSb = wsu + o; o += (size_t)8 * 1024 * 512; // hq x8 / gate x4 bf16 partials
    float* wsf    = (float*)(wsu + o);
    float* hqf    = wsf;                   // 524288
    float* epart  = hqf + 524288;          // 40960*4
    // LSTM bf16 partials (4 x 1024 x 4096 ushort = 32 MB) alias Vb (dead after softmax_af)
    ushort* partKb = Vb;

    const dim3 blk(256);

    // ---- conversion / transpose passes ----
    conv_bf16_kernel<<<dim3(20480), blk, 0, stream>>>(V, Vb, 5242880);
    {
        CP3 p; p.in[0] = xt; p.in[1] = h1; p.in[2] = h2;
        p.out[0] = xtb; p.out[1] = h1b; p.out[2] = h2b;
        conv_bf16_batch3_kernel<<<dim3(512, 3), blk, 0, stream>>>(p, 131072);
    }
    {
        TP6 p;
        p.in[0] = Wi1; p.in[1] = Wa1; p.in[2] = Wh1;
        p.in[3] = Wi2; p.in[4] = Wa2; p.in[5] = Wh2;
        p.out[0] = Wi1T; p.out[1] = Wa1T; p.out[2] = Wh1T;
        p.out[3] = Wi2T; p.out[4] = Wa2T; p.out[5] = Wh2T;
        for (int z = 0; z < 6; ++z) p.N[z] = 4096;
        transpose_conv_kernel<<<dim3(64, 16, 6), blk, 0, stream>>>(p);
    }
    {
        TP6 p;
        p.in[0] = Wh2a; p.in[1] = Wh2a + (size_t)1024 * 512;
        p.in[2] = Wg;   p.in[3] = Wv2a;
        p.out[0] = Wh2aT0; p.out[1] = Wh2aT1; p.out[2] = WgT; p.out[3] = Wv2aT;
        p.N[0] = 512; p.N[1] = 512; p.N[2] = 1024; p.N[3] = 512;
        p.in[4] = nullptr; p.in[5] = nullptr; p.out[4] = nullptr; p.out[5] = nullptr;
        p.N[4] = 0; p.N[5] = 0;
        transpose_conv_kernel<<<dim3(16, 16, 4), blk, 0, stream>>>(p);
    }

    // ---- hq = [h1,h2] @ Wh2a (split-K x8, bf16 partials) + bias reduce ----
    gemm_gl<2, 8><<<dim3(4, 8, 8), blk, 0, stream>>>(
        h1b, h2b, nullptr, Wh2aT0, Wh2aT1, nullptr, partSb, 1024, 512);
    reduce_hq_b_kernel<<<dim3(2048), blk, 0, stream>>>(partSb, bh2a, hqf);

    // ---- gate: xt @ Wg (split-K x4, bf16 partials), relu*pos+pos -> bf16 ----
    gemm_gl<1, 4><<<dim3(8, 8, 4), blk, 0, stream>>>(
        xtb, nullptr, nullptr, WgT, nullptr, nullptr, partSb, 1024, 1024);
    reduce_gate_b_kernel<<<dim3(4096), blk, 0, stream>>>(partSb, bg, pos, gpb);

    // ---- attention scores: dbuf Vb @ Wv2a, fused tanh-reduce -> epart ----
    attn_db<<<dim3(4, 320), blk, 0, stream>>>(
        Vb, Wv2aT, hqf, bv2a, Wa2w, epart);
    softmax_af_kernel<<<dim3(BB), blk, 0, stream>>>(epart, Vb, ba2w, afb);

    // ---- LSTM layer 1 (split-K x4 over fused K = xt|gp|h1, bf16 partials) ----
    gemm_gl<3, 4><<<dim3(32, 8, 4), blk, 0, stream>>>(
        xtb, gpb, h1b, Wi1T, Wa1T, Wh1T, partKb, 1024, 4096);
    lstm_finishb_kernel<<<dim3(4096), blk, 0, stream>>>(
        partKb, bi1, ba1, bh1, c1, h1, mask, out1, nullptr, c1n, out1b);

    // ---- LSTM layer 2 (split-K x4 over fused K = out1|af|h2) ----
    gemm_gl<3, 4><<<dim3(32, 8, 4), blk, 0, stream>>>(
        out1b, afb, h2b, Wi2T, Wa2T, Wh2T, partKb, 1024, 4096);
    lstm_finishb_kernel<<<dim3(4096), blk, 0, stream>>>(
        partKb, bi2, ba2, bh2, c2, h2, mask, out2, out2b, c2n, nullptr);
}

// Round 15
// 312.965 us; speedup vs baseline: 1.3127x; 1.0469x over previous
//
#include <hip/hip_runtime.h>
#include <math.h>

#define BB 1024
#define LL 40
#define RR 1024

using short8 = __attribute__((ext_vector_type(8))) short;
using us8    = __attribute__((ext_vector_type(8))) unsigned short;
using f32x4  = __attribute__((ext_vector_type(4))) float;

__device__ __forceinline__ ushort f2bf(float f) {
    union { float f; unsigned u; } a; a.f = f;
    unsigned r = a.u + 0x7fffu + ((a.u >> 16) & 1u);  // RNE
    return (ushort)(r >> 16);
}
__device__ __forceinline__ float bf2f(ushort u) {
    union { unsigned u; float f; } a; a.u = ((unsigned)u) << 16;
    return a.f;
}
__device__ __forceinline__ float ftanh(float x) {
    float cx = fminf(fmaxf(x, -15.f), 15.f);
    float e = __expf(2.f * cx);
    return (e - 1.f) / (e + 1.f);
}
__device__ __forceinline__ float fsigmoid(float x) {
    float cx = fminf(fmaxf(x, -30.f), 30.f);
    return 1.f / (1.f + __expf(-cx));
}

__device__ __forceinline__ void gll16(const ushort* g, ushort* l) {
    __builtin_amdgcn_global_load_lds(
        (const __attribute__((address_space(1))) void*)g,
        (__attribute__((address_space(3))) void*)l,
        16, 0, 0);
}

// ---------------------------------------------------------------------------
__global__ __launch_bounds__(256) void conv_bf16_kernel(
    const float* __restrict__ src, ushort* __restrict__ dst, int n8)
{
    const int i = blockIdx.x * 256 + threadIdx.x;
    if (i >= n8) return;
    const float4* s4 = (const float4*)(src + (size_t)i * 8);
    float4 x = s4[0], y = s4[1];
    us8 v;
    v[0] = f2bf(x.x); v[1] = f2bf(x.y); v[2] = f2bf(x.z); v[3] = f2bf(x.w);
    v[4] = f2bf(y.x); v[5] = f2bf(y.y); v[6] = f2bf(y.z); v[7] = f2bf(y.w);
    ((us8*)dst)[i] = v;
}

struct CP3 { const float* in[3]; ushort* out[3]; };
__global__ __launch_bounds__(256) void conv_bf16_batch3_kernel(CP3 p, int n8)
{
    const int z = blockIdx.y;
    const int i = blockIdx.x * 256 + threadIdx.x;
    if (i >= n8) return;
    const float4* s4 = (const float4*)(p.in[z] + (size_t)i * 8);
    float4 x = s4[0], y = s4[1];
    us8 v;
    v[0] = f2bf(x.x); v[1] = f2bf(x.y); v[2] = f2bf(x.z); v[3] = f2bf(x.w);
    v[4] = f2bf(y.x); v[5] = f2bf(y.y); v[6] = f2bf(y.z); v[7] = f2bf(y.w);
    ((us8*)p.out[z])[i] = v;
}

struct TP6 { const float* in[6]; ushort* out[6]; int N[6]; };
__global__ __launch_bounds__(256) void transpose_conv_kernel(TP6 p)
{
    const int z = blockIdx.z;
    const int Nn = p.N[z];
    const int n0 = blockIdx.x * 64;
    if (n0 >= Nn) return;
    const int k0 = blockIdx.y * 64;
    const float* in = p.in[z];
    ushort* out = p.out[z];

    __shared__ float tile[64][65];
    const int t = threadIdx.x;
    const int tx = t & 63, ty = t >> 6;
#pragma unroll
    for (int r = 0; r < 16; ++r) {
        const int row = ty * 16 + r;
        tile[row][tx] = in[(size_t)(k0 + row) * Nn + n0 + tx];
    }
    __syncthreads();
    const int n = t >> 2, kq = t & 3;
    us8 v0, v1;
#pragma unroll
    for (int j = 0; j < 8; ++j) v0[j] = f2bf(tile[kq * 16 + j][n]);
#pragma unroll
    for (int j = 0; j < 8; ++j) v1[j] = f2bf(tile[kq * 16 + 8 + j][n]);
    ushort* op = out + (size_t)(n0 + n) * 1024 + k0 + kq * 16;
    *(us8*)op = v0;
    *((us8*)op + 1) = v1;
}

// ---------------------------------------------------------------------------
// R8-proven 128x128 BK=64 4-wave GEMM (single-buffer, XOR swizzle, 0 bank
// conflicts). For hq/gate/LSTM. bf16 split-K partial store.
// ---------------------------------------------------------------------------
template <int NP, int SK>
__global__ __launch_bounds__(256) void gemm_gl(
    const ushort* __restrict__ A0, const ushort* __restrict__ A1, const ushort* __restrict__ A2,
    const ushort* __restrict__ W0, const ushort* __restrict__ W1, const ushort* __restrict__ W2,
    ushort* __restrict__ Cp, int M, int N)
{
    __shared__ ushort As[128 * 64];
    __shared__ ushort Bs[128 * 64];

    const int t = threadIdx.x, l = t & 63, w = t >> 6;
    const int wm = w >> 1, wn = w & 1;
    const int m0 = blockIdx.y * 128, n0 = blockIdx.x * 128;

    const int srow = l >> 3;
    const int csw  = ((l & 7) ^ (l >> 3)) * 8;
    const int kx0 = ((0 + (l >> 4)) ^ (l & 7)) * 8;
    const int kx1 = ((4 + (l >> 4)) ^ (l & 7)) * 8;

    f32x4 acc[4][4];
#pragma unroll
    for (int i = 0; i < 4; ++i)
#pragma unroll
        for (int j = 0; j < 4; ++j) acc[i][j] = (f32x4){0.f, 0.f, 0.f, 0.f};

    const int total = NP * 16;
    const int per   = total / SK;
    const int s0v   = blockIdx.z * per;
    const int sEnd  = s0v + per;

    for (int s = s0v; s < sEnd; ++s) {
        const int p  = (NP == 1) ? 0 : (s >> 4);
        const int k0 = (s & 15) << 6;
        const ushort* Ap = (p == 0) ? A0 : ((p == 1) ? A1 : A2);
        const ushort* Wp = (p == 0) ? W0 : ((p == 1) ? W1 : W2);
#pragma unroll
        for (int j = 0; j < 4; ++j) {
            const int rb = w * 32 + j * 8;
            gll16(Ap + (size_t)(m0 + rb + srow) * 1024 + k0 + csw, &As[rb * 64]);
            gll16(Wp + (size_t)(n0 + rb + srow) * 1024 + k0 + csw, &Bs[rb * 64]);
        }
        __syncthreads();

        short8 aF[4][2], bF[4][2];
#pragma unroll
        for (int mi = 0; mi < 4; ++mi) {
            const int ro = (wm * 64 + mi * 16 + (l & 15)) * 64;
            aF[mi][0] = *(const short8*)&As[ro + kx0];
            aF[mi][1] = *(const short8*)&As[ro + kx1];
        }
#pragma unroll
        for (int ni = 0; ni < 4; ++ni) {
            const int ro = (wn * 64 + ni * 16 + (l & 15)) * 64;
            bF[ni][0] = *(const short8*)&Bs[ro + kx0];
            bF[ni][1] = *(const short8*)&Bs[ro + kx1];
        }
#pragma unroll
        for (int mi = 0; mi < 4; ++mi)
#pragma unroll
            for (int ni = 0; ni < 4; ++ni) {
                acc[mi][ni] = __builtin_amdgcn_mfma_f32_16x16x32_bf16(
                    aF[mi][0], bF[ni][0], acc[mi][ni], 0, 0, 0);
                acc[mi][ni] = __builtin_amdgcn_mfma_f32_16x16x32_bf16(
                    aF[mi][1], bF[ni][1], acc[mi][ni], 0, 0, 0);
            }
        __syncthreads();
    }

    ushort* Cz = Cp + (size_t)blockIdx.z * M * N;
#pragma unroll
    for (int ni = 0; ni < 4; ++ni) {
        const int col = n0 + wn * 64 + ni * 16 + (l & 15);
#pragma unroll
        for (int mi = 0; mi < 4; ++mi) {
            const int row = m0 + wm * 64 + mi * 16 + ((l >> 4) << 2);
#pragma unroll
            for (int r = 0; r < 4; ++r)
                Cz[(size_t)(row + r) * N + col] = f2bf(acc[mi][ni][r]);
        }
    }
}

// ---------------------------------------------------------------------------
// R10/R12-proven attn GEMM: 128x128 BK=32 dbuf, counted vmcnt(4) prefetch,
// pair-swizzle LDS (0 bank conflicts). Fused tanh*Wa2w epilogue.
// ---------------------------------------------------------------------------
__global__ __launch_bounds__(256) void attn_db(
    const ushort* __restrict__ A0, const ushort* __restrict__ W0,
    const float* __restrict__ hq, const float* __restrict__ bv2a,
    const float* __restrict__ Wa2w, float* __restrict__ epart)
{
    __shared__ ushort As[2][128 * 32];   // 2 x 8 KB
    __shared__ ushort Bs[2][128 * 32];   // 2 x 8 KB

    const int t = threadIdx.x, l = t & 63, w = t >> 6;
    const int wm = w >> 1, wn = w & 1;

    // XCD-chunked bijective swizzle: nwg = 4*320 = 1280 = 8*160
    const int lin = blockIdx.y * gridDim.x + blockIdx.x;
    const int swz = (lin & 7) * 160 + (lin >> 3);
    const int bx = swz & 3, by = swz >> 2;
    const int m0 = by * 128, n0 = bx * 128;

    const int srow  = l >> 2;
    const int schnk = ((l & 3) ^ ((l >> 3) & 3)) * 8;

    int aoff[4], boff[4];
#pragma unroll
    for (int mi = 0; mi < 4; ++mi)
        aoff[mi] = (wm * 64 + mi * 16 + (l & 15)) * 32 + (((l >> 4) ^ ((l >> 1) & 3)) * 8);
#pragma unroll
    for (int ni = 0; ni < 4; ++ni)
        boff[ni] = (wn * 64 + ni * 16 + (l & 15)) * 32 + (((l >> 4) ^ ((l >> 1) & 3)) * 8);

    f32x4 acc[4][4];
#pragma unroll
    for (int i = 0; i < 4; ++i)
#pragma unroll
        for (int j = 0; j < 4; ++j) acc[i][j] = (f32x4){0.f, 0.f, 0.f, 0.f};

    auto stage = [&](int s, int buf) {   // 4 gll16 per thread
        const int k0 = s << 5;
#pragma unroll
        for (int j = 0; j < 2; ++j) {
            const int rb = j * 64 + w * 16;
            gll16(A0 + (size_t)(m0 + rb + srow) * 1024 + k0 + schnk, &As[buf][rb * 32]);
            gll16(W0 + (size_t)(n0 + rb + srow) * 1024 + k0 + schnk, &Bs[buf][rb * 32]);
        }
    };

    constexpr int NS = 32;               // K-steps of 32 (K = 1024)
    stage(0, 0);
    int cur = 0;
    for (int s = 0; s < NS; ++s) {
        const bool pf = (s + 1 < NS);
        if (pf) {
            stage(s + 1, cur ^ 1);        // up to 8 outstanding
            asm volatile("s_waitcnt vmcnt(4)" ::: "memory");   // retire tile s
        } else {
            asm volatile("s_waitcnt vmcnt(0)" ::: "memory");
        }
        __builtin_amdgcn_s_barrier();     // buffer cur resident for all waves
        asm volatile("" ::: "memory");

        short8 aF[4], bF[4];
#pragma unroll
        for (int mi = 0; mi < 4; ++mi) aF[mi] = *(const short8*)&As[cur][aoff[mi]];
#pragma unroll
        for (int ni = 0; ni < 4; ++ni) bF[ni] = *(const short8*)&Bs[cur][boff[ni]];
#pragma unroll
        for (int mi = 0; mi < 4; ++mi)
#pragma unroll
            for (int ni = 0; ni < 4; ++ni)
                acc[mi][ni] = __builtin_amdgcn_mfma_f32_16x16x32_bf16(
                    aF[mi], bF[ni], acc[mi][ni], 0, 0, 0);

        asm volatile("" ::: "memory");
        __builtin_amdgcn_s_barrier();     // all waves done reading cur
        asm volatile("" ::: "memory");
        cur ^= 1;
    }

    // ---- fused epilogue: tanh(acc + hq + bv2a) * Wa2w reduced over 128 cols
    float* red = (float*)&As[0][0];       // [128][2]
    float wa[4], bv[4];
    int coln[4];
#pragma unroll
    for (int ni = 0; ni < 4; ++ni) {
        coln[ni] = n0 + wn * 64 + ni * 16 + (l & 15);
        wa[ni] = Wa2w[coln[ni]];
        bv[ni] = bv2a[coln[ni]];
    }
#pragma unroll
    for (int mi = 0; mi < 4; ++mi) {
        const int rowl = wm * 64 + mi * 16 + ((l >> 4) << 2);
#pragma unroll
        for (int r = 0; r < 4; ++r) {
            const int row = m0 + rowl + r;
            const int b = row / LL;
            float v = 0.f;
#pragma unroll
            for (int ni = 0; ni < 4; ++ni) {
                float x = acc[mi][ni][r] + hq[(size_t)b * 512 + coln[ni]] + bv[ni];
                v += ftanh(x) * wa[ni];
            }
            v += __shfl_xor(v, 1);
            v += __shfl_xor(v, 2);
            v += __shfl_xor(v, 4);
            v += __shfl_xor(v, 8);
            if ((l & 15) == 0) red[(rowl + r) * 2 + wn] = v;
        }
    }
    __syncthreads();
    if (t < 128)
        epart[(size_t)(m0 + t) * 4 + bx] = red[t * 2] + red[t * 2 + 1];
}

// ---------------------------------------------------------------------------
__global__ __launch_bounds__(256) void reduce_hq_b_kernel(
    const ushort* __restrict__ part, const float* __restrict__ bias, float* __restrict__ hq)
{
    const int i = blockIdx.x * 256 + threadIdx.x;   // < 1024*512
    float s = bias[i & 511];
#pragma unroll
    for (int z = 0; z < 8; ++z) s += bf2f(part[(size_t)z * 524288 + i]);
    hq[i] = s;
}

__global__ __launch_bounds__(256) void reduce_gate_b_kernel(
    const ushort* __restrict__ part, const float* __restrict__ bias,
    const float* __restrict__ pos, ushort* __restrict__ gpb)
{
    const int i = blockIdx.x * 256 + threadIdx.x;   // < 1024*1024
    float s = bias[i & 1023];
#pragma unroll
    for (int z = 0; z < 4; ++z) s += bf2f(part[(size_t)z * 1048576 + i]);
    const float g = fmaxf(s, 0.f);
    gpb[i] = f2bf(g * pos[i] + pos[i]);
}

// ---------------------------------------------------------------------------
__global__ __launch_bounds__(256) void softmax_af_kernel(
    const float* __restrict__ epart, const ushort* __restrict__ Vb,
    const float* __restrict__ ba2w, ushort* __restrict__ afb)
{
    const int b = blockIdx.x;
    const int tid = threadIdx.x;
    __shared__ float e_raw[LL];
    __shared__ float e_exp[LL];

    if (tid < LL) {
        const float* ep = &epart[(size_t)(b * LL + tid) * 4];
        float e = ba2w[0];
#pragma unroll
        for (int c = 0; c < 4; ++c) e += ep[c];
        e_raw[tid] = e;
    }
    __syncthreads();
    float mx = -1e30f;
#pragma unroll
    for (int ll = 0; ll < LL; ++ll) mx = fmaxf(mx, e_raw[ll]);
    if (tid < LL) e_exp[tid] = __expf(e_raw[tid] - mx);
    __syncthreads();
    float sum = 0.f;
#pragma unroll
    for (int ll = 0; ll < LL; ++ll) sum += e_exp[ll];
    const float inv = 1.f / sum;

    const int r4 = tid * 4;
    const ushort* vp = &Vb[(size_t)b * LL * RR + r4];
    float a0 = 0.f, a1 = 0.f, a2 = 0.f, a3 = 0.f;
#pragma unroll 8
    for (int ll = 0; ll < LL; ++ll) {
        ushort4 v = *(const ushort4*)&vp[(size_t)ll * RR];
        const float wgt = e_exp[ll];
        a0 += wgt * bf2f(v.x); a1 += wgt * bf2f(v.y);
        a2 += wgt * bf2f(v.z); a3 += wgt * bf2f(v.w);
    }
    ushort* op = &afb[(size_t)b * RR + r4];
    op[0] = f2bf(a0 * inv); op[1] = f2bf(a1 * inv);
    op[2] = f2bf(a2 * inv); op[3] = f2bf(a3 * inv);
}

// ---------------------------------------------------------------------------
__global__ __launch_bounds__(256) void lstm_finishb_kernel(
    const ushort* __restrict__ part,
    const float* __restrict__ bi, const float* __restrict__ ba, const float* __restrict__ bh,
    const float* __restrict__ c_in, const float* __restrict__ h_in, const float* __restrict__ mask,
    float* __restrict__ h_out, float* __restrict__ h_out2,
    float* __restrict__ c_out, ushort* __restrict__ h_bf)
{
    const int i = blockIdx.x * 256 + threadIdx.x;  // [0, B*R)
    const int b = i >> 10;
    const int r = i & 1023;
    float sg[4];
#pragma unroll
    for (int g = 0; g < 4; ++g) {
        const int gr = g * 1024 + r;
        float s = bi[gr] + ba[gr] + bh[gr];
#pragma unroll
        for (int z = 0; z < 4; ++z)
            s += bf2f(part[(size_t)z * 4194304 + (size_t)b * 4096 + gr]);
        sg[g] = s;
    }
    const float ig = fsigmoid(sg[0]);
    const float fg = fsigmoid(sg[1]);
    const float og = fsigmoid(sg[2]);
    const float gt = ftanh(sg[3]);
    const float m = mask[b];
    const float c = c_in[i];
    float cn = fg * c + ig * gt;
    cn = cn * m + c * (1.f - m);
    const float h = h_in[i];
    float hn = og * ftanh(cn);
    hn = hn * m + h * (1.f - m);
    h_out[i] = hn;
    if (h_out2) h_out2[i] = hn;
    c_out[i] = cn;
    if (h_bf) h_bf[i] = f2bf(hn);
}

extern "C" void kernel_launch(void* const* d_in, const int* in_sizes, int n_in,
                              void* d_out, int out_size, void* d_ws, size_t ws_size,
                              hipStream_t stream) {
    const float* xt   = (const float*)d_in[0];
    const float* mask = (const float*)d_in[1];
    const float* V    = (const float*)d_in[2];
    const float* pos  = (const float*)d_in[3];
    const float* h1   = (const float*)d_in[4];
    const float* c1   = (const float*)d_in[5];
    const float* h2   = (const float*)d_in[6];
    const float* c2   = (const float*)d_in[7];
    const float* Wg   = (const float*)d_in[8];
    const float* bg   = (const float*)d_in[9];
    const float* Wi1  = (const float*)d_in[10];
    const float* bi1  = (const float*)d_in[11];
    const float* Wa1  = (const float*)d_in[12];
    const float* ba1  = (const float*)d_in[13];
    const float* Wh1  = (const float*)d_in[14];
    const float* bh1  = (const float*)d_in[15];
    const float* Wi2  = (const float*)d_in[16];
    const float* bi2  = (const float*)d_in[17];
    const float* Wa2  = (const float*)d_in[18];
    const float* ba2  = (const float*)d_in[19];
    const float* Wh2  = (const float*)d_in[20];
    const float* bh2  = (const float*)d_in[21];
    const float* Wv2a = (const float*)d_in[22];
    const float* bv2a = (const float*)d_in[23];
    const float* Wh2a = (const float*)d_in[24];
    const float* bh2a = (const float*)d_in[25];
    const float* Wa2w = (const float*)d_in[26];
    const float* ba2w = (const float*)d_in[27];

    float* out = (float*)d_out;
    float* out2  = out;
    float* out1  = out + (size_t)BB * RR;
    float* c1n   = out + 2 * (size_t)BB * RR;
    float* out2b = out + 3 * (size_t)BB * RR;
    float* c2n   = out + 4 * (size_t)BB * RR;

    // ---- workspace ----
    ushort* wsu = (ushort*)d_ws;
    size_t o = 0;
    ushort* Vb     = wsu + o; o += (size_t)40960 * 1024;   // 84 MB
    ushort* Wh2aT0 = wsu + o; o += (size_t)512 * 1024;
    ushort* Wh2aT1 = wsu + o; o += (size_t)512 * 1024;
    ushort* WgT    = wsu + o; o += (size_t)1024 * 1024;
    ushort* Wv2aT  = wsu + o; o += (size_t)512 * 1024;
    ushort* Wi1T   = wsu + o; o += (size_t)4096 * 1024;
    ushort* Wa1T   = wsu + o; o += (size_t)4096 * 1024;
    ushort* Wh1T   = wsu + o; o += (size_t)4096 * 1024;
    ushort* Wi2T   = wsu + o; o += (size_t)4096 * 1024;
    ushort* Wa2T   = wsu + o; o += (size_t)4096 * 1024;
    ushort* Wh2T   = wsu + o; o += (size_t)4096 * 1024;
    ushort* xtb    = wsu + o; o += (size_t)1024 * 1024;
    ushort* h1b    = wsu + o; o += (size_t)1024 * 1024;
    ushort* h2b    = wsu + o; o += (size_t)1024 * 1024;
    ushort* gpb    = wsu + o; o += (size_t)1024 * 1024;
    ushort* afb    = wsu + o; o += (size_t)1024 * 1024;
    ushort* out1b  = wsu + o; o += (size_t)1024 * 1024;
    ushort* partSb = wsu + o; o += (size_t)8 * 1024 * 512; // hq x8 / gate x4 bf16 partials
    float* wsf    = (float*)(wsu + o);
    float* hqf    = wsf;                   // 524288
    float* epart  = hqf + 524288;          // 40960*4
    // LSTM bf16 partials (4 x 1024 x 4096 ushort = 32 MB) alias Vb (dead after softmax_af)
    ushort* partKb = Vb;

    const dim3 blk(256);

    // ---- conversion / transpose passes ----
    conv_bf16_kernel<<<dim3(20480), blk, 0, stream>>>(V, Vb, 5242880);
    {
        CP3 p; p.in[0] = xt; p.in[1] = h1; p.in[2] = h2;
        p.out[0] = xtb; p.out[1] = h1b; p.out[2] = h2b;
        conv_bf16_batch3_kernel<<<dim3(512, 3), blk, 0, stream>>>(p, 131072);
    }
    {
        TP6 p;
        p.in[0] = Wi1; p.in[1] = Wa1; p.in[2] = Wh1;
        p.in[3] = Wi2; p.in[4] = Wa2; p.in[5] = Wh2;
        p.out[0] = Wi1T; p.out[1] = Wa1T; p.out[2] = Wh1T;
        p.out[3] = Wi2T; p.out[4] = Wa2T; p.out[5] = Wh2T;
        for (int z = 0; z < 6; ++z) p.N[z] = 4096;
        transpose_conv_kernel<<<dim3(64, 16, 6), blk, 0, stream>>>(p);
    }
    {
        TP6 p;
        p.in[0] = Wh2a; p.in[1] = Wh2a + (size_t)1024 * 512;
        p.in[2] = Wg;   p.in[3] = Wv2a;
        p.out[0] = Wh2aT0; p.out[1] = Wh2aT1; p.out[2] = WgT; p.out[3] = Wv2aT;
        p.N[0] = 512; p.N[1] = 512; p.N[2] = 1024; p.N[3] = 512;
        p.in[4] = nullptr; p.in[5] = nullptr; p.out[4] = nullptr; p.out[5] = nullptr;
        p.N[4] = 0; p.N[5] = 0;
        transpose_conv_kernel<<<dim3(16, 16, 4), blk, 0, stream>>>(p);
    }

    // ---- hq = [h1,h2] @ Wh2a (split-K x8, bf16 partials) + bias reduce ----
    gemm_gl<2, 8><<<dim3(4, 8, 8), blk, 0, stream>>>(
        h1b, h2b, nullptr, Wh2aT0, Wh2aT1, nullptr, partSb, 1024, 512);
    reduce_hq_b_kernel<<<dim3(2048), blk, 0, stream>>>(partSb, bh2a, hqf);

    // ---- gate: xt @ Wg (split-K x4, bf16 partials), relu*pos+pos -> bf16 ----
    gemm_gl<1, 4><<<dim3(8, 8, 4), blk, 0, stream>>>(
        xtb, nullptr, nullptr, WgT, nullptr, nullptr, partSb, 1024, 1024);
    reduce_gate_b_kernel<<<dim3(4096), blk, 0, stream>>>(partSb, bg, pos, gpb);

    // ---- attention scores: dbuf Vb @ Wv2a, fused tanh-reduce -> epart ----
    attn_db<<<dim3(4, 320), blk, 0, stream>>>(
        Vb, Wv2aT, hqf, bv2a, Wa2w, epart);
    softmax_af_kernel<<<dim3(BB), blk, 0, stream>>>(epart, Vb, ba2w, afb);

    // ---- LSTM layer 1 (split-K x4 over fused K = xt|gp|h1, bf16 partials) ----
    gemm_gl<3, 4><<<dim3(32, 8, 4), blk, 0, stream>>>(
        xtb, gpb, h1b, Wi1T, Wa1T, Wh1T, partKb, 1024, 4096);
    lstm_finishb_kernel<<<dim3(4096), blk, 0, stream>>>(
        partKb, bi1, ba1, bh1, c1, h1, mask, out1, nullptr, c1n, out1b);

    // ---- LSTM layer 2 (split-K x4 over fused K = out1|af|h2) ----
    gemm_gl<3, 4><<<dim3(32, 8, 4), blk, 0, stream>>>(
        out1b, afb, h2b, Wi2T, Wa2T, Wh2T, partKb, 1024, 4096);
    lstm_finishb_kernel<<<dim3(4096), blk, 0, stream>>>(
        partKb, bi2, ba2, bh2, c2, h2, mask, out2, out2b, c2n, nullptr);
}